// Round 15
// baseline (112.719 us; speedup 1.0000x reference)
//
#include <hip/hip_runtime.h>
#include <math.h>

#define NB      8192
#define ND      2048
#define NC      100
#define NCP     112
#define ALPHA_  2.0f
#define MARGIN_ 0.05f

typedef short bf16x8 __attribute__((ext_vector_type(8)));
typedef float f32x4 __attribute__((ext_vector_type(4)));

static __device__ __forceinline__ unsigned short f2bf(float f) {
  unsigned u = __float_as_uint(f);
  u += 0x7FFFu + ((u >> 16) & 1u);
  return (unsigned short)(u >> 16);
}

// ---- prepA: [0,112) Wtf transpose | [112,912) Gp/pap K-split partials ------
//      | 912: zero cls_ap/hist/sums strip (384 floats)
__global__ __launch_bounds__(256) void k_prepA(const float* __restrict__ W,
                                               const float* __restrict__ A,
                                               unsigned short* __restrict__ Wtf,
                                               float* __restrict__ Gp,
                                               float* __restrict__ pap,
                                               float* __restrict__ zstrip) {
  __shared__ float wcol[256];
  __shared__ float arow[256];
  const int bid = blockIdx.x;
  const int t   = threadIdx.x;
  if (bid < 112) {
    const int f   = bid * 256 + t;   // 0..28671
    const int ws  = f / 448;
    const int rem = f - ws * 448;
    const int i   = rem >> 6;
    const int l   = rem & 63;
    const int col = i * 16 + (l & 15);
    const int k0  = ws * 32 + (l >> 4) * 8;
    bf16x8 v;
#pragma unroll
    for (int j = 0; j < 8; ++j)
      v[j] = (short)((col < NC) ? f2bf(W[(size_t)(k0 + j) * NC + col]) : 0);
    *(bf16x8*)(Wtf + (size_t)f * 8) = v;
  } else if (bid < 912) {
    const int idx = bid - 112;   // 0..799
    const int r   = idx >> 3;    // 0..99
    const int ks  = idx & 7;     // K-slice of 256
    const int k0  = ks * 256;
    wcol[t] = W[(size_t)(k0 + t) * NC + r];
    arow[t] = A[(size_t)r * ND + k0 + t];
    __syncthreads();
    if (t < NC) {
      float g = 0.f, p = 0.f;
#pragma unroll 8
      for (int kk = 0; kk < 256; ++kk) {
        const float w = W[(size_t)(k0 + kk) * NC + t];
        g = fmaf(wcol[kk], w, g);
        p = fmaf(arow[kk], w, p);
      }
      Gp[(size_t)(ks * NC + r) * NCP + t]  = g;   // plain stores, no atomics
      pap[(size_t)(ks * NC + r) * NCP + t] = p;
    }
  } else {
    for (int i = t; i < 384; i += 256) zstrip[i] = 0.f;  // cls_ap, hist, sums
  }
}

// ---- prep2: hist + pa row (8 partial sums) + softmax + Ut from Gp ----------
__global__ __launch_bounds__(128) void k_prep2(const float* __restrict__ Gp,
                                               const float* __restrict__ pap,
                                               const int* __restrict__ Y,
                                               float* __restrict__ Ut,
                                               int* __restrict__ hist) {
  __shared__ float vals[128];
  __shared__ float tl[128];
  const int cp = blockIdx.x;
  const int t  = threadIdx.x;
  {
    const int i = cp * 82 + t;
    if (t < 82 && i < NB) atomicAdd(&hist[Y[i]], 1);
  }
  float v = -INFINITY;
  if (t < NC) {
    float s = 0.f;
#pragma unroll
    for (int ks = 0; ks < 8; ++ks)
      s += pap[(size_t)(ks * NC + cp) * NCP + t];
    v = s;
  }
  vals[t] = v;
  __syncthreads();
  float m = -INFINITY;
  for (int c = 0; c < NC; ++c) m = fmaxf(m, vals[c]);
  float se = 0.f;
  for (int c = 0; c < NC; ++c) se += __expf(vals[c] - m);
  tl[t] = (t < NC) ? (__expf(v - m) / se - (t == cp ? 1.f : 0.f)) : 0.f;
  __syncthreads();
  if (t < NC) {
    float u = 0.f;
#pragma unroll
    for (int ks = 0; ks < 8; ++ks) {
      const float* __restrict__ gp = Gp + (size_t)ks * NC * NCP;
#pragma unroll 4
      for (int c = 0; c < NC; ++c) u = fmaf(gp[c * NCP + t], tl[c], u);
    }
    Ut[cp * NC + t] = u;
  }
}

// ---- main: r10 verbatim — 8 waves x 256-K, B dbuf, atomic-free store tail --
__global__ __launch_bounds__(512, 4) void k_main(const float* __restrict__ X,
                                                 const unsigned short* __restrict__ Wtf,
                                                 const int* __restrict__ Y,
                                                 const float* __restrict__ Ut,
                                                 float* __restrict__ S_part,
                                                 float* __restrict__ rowce,
                                                 float* __restrict__ rowap) {
  __shared__ __align__(16) char smem[65536];  // 8 x 8KB wave slabs; reused
  const int t    = threadIdx.x;
  const int w    = t >> 6;     // wave 0..7 = K-slice (256 K each)
  const int lane = t & 63;
  const int row0 = blockIdx.x * 16;
  char* __restrict__ wbase = smem + w * 8192;

  // issue first B-fragment batch BEFORE the X stage (independent of LDS)
  const unsigned short* __restrict__ bp0 =
      Wtf + (size_t)(w * 8 * 7) * 512 + lane * 8;
  bf16x8 cur[7], nxt[7];
#pragma unroll
  for (int i = 0; i < 7; ++i) cur[i] = *(const bf16x8*)(bp0 + i * 512);

  // ---- per-wave stage: 16 rows x 256 K, f32 -> bf16, XOR-swizzled [row][k] --
  {
    const int srow = lane >> 2;
    const int sc   = lane & 3;
    const float* __restrict__ xr =
        X + (size_t)(row0 + srow) * ND + w * 256 + sc * 8;
    const int wsz = (srow & 7) << 4;
#pragma unroll
    for (int j = 0; j < 8; ++j) {
      const float4 v0 = *(const float4*)(xr + j * 32);
      const float4 v1 = *(const float4*)(xr + j * 32 + 4);
      bf16x8 p;
      p[0] = (short)f2bf(v0.x); p[1] = (short)f2bf(v0.y);
      p[2] = (short)f2bf(v0.z); p[3] = (short)f2bf(v0.w);
      p[4] = (short)f2bf(v1.x); p[5] = (short)f2bf(v1.y);
      p[6] = (short)f2bf(v1.z); p[7] = (short)f2bf(v1.w);
      *(bf16x8*)(wbase + srow * 512 + ((sc * 16 + j * 64) ^ wsz)) = p;
    }
  }
  // no barrier: slab is wave-private (ds_write->ds_read ordered in-wave)

  const int r = lane & 15;
  const int g = lane >> 4;

  f32x4 acc[7];
  const f32x4 z = {0.f, 0.f, 0.f, 0.f};
#pragma unroll
  for (int i = 0; i < 7; ++i) acc[i] = z;

  const char* __restrict__ abase = wbase + r * 512;
  const int asz = (r & 7) << 4;
#pragma unroll
  for (int s = 0; s < 8; ++s) {
    const bf16x8 xf = *(const bf16x8*)(abase + ((s * 64 + g * 16) ^ asz));
    if (s < 7) {
      const unsigned short* __restrict__ bpn = bp0 + (size_t)(s + 1) * 7 * 512;
#pragma unroll
      for (int i = 0; i < 7; ++i) nxt[i] = *(const bf16x8*)(bpn + i * 512);
    }
#pragma unroll
    for (int i = 0; i < 7; ++i)
      acc[i] = __builtin_amdgcn_mfma_f32_16x16x32_bf16(xf, cur[i], acc[i], 0, 0, 0);
#pragma unroll
    for (int i = 0; i < 7; ++i) cur[i] = nxt[i];
  }
  __syncthreads();  // all waves done with slabs -> reuse for reduction

  float* __restrict__ redp = (float*)smem;            // [8][7][4][64] = 57344 B
  float* __restrict__ sp   = (float*)(smem + 57344);  // [112] column partials
#pragma unroll
  for (int i = 0; i < 7; ++i)
#pragma unroll
    for (int j = 0; j < 4; ++j)
      redp[(w * 7 + i) * 256 + j * 64 + lane] = acc[i][j];
  if (t < NCP) sp[t] = 0.f;
  __syncthreads();

  // epilogue: waves 0..3 each own j = w (rows g*4 + j)
  if (w < 4) {
    const int j = w;
    float v[7];
#pragma unroll
    for (int i = 0; i < 7; ++i) {
      float s = 0.f;
#pragma unroll
      for (int w2 = 0; w2 < 8; ++w2)
        s += redp[(w2 * 7 + i) * 256 + j * 64 + lane];
      v[i] = s;
    }
    const bool v6  = (96 + r) < NC;
    const int  row = row0 + g * 4 + j;
    const int  yr  = Y[row];

    float m = -INFINITY;
#pragma unroll
    for (int i = 0; i < 6; ++i) m = fmaxf(m, v[i]);
    if (v6) m = fmaxf(m, v[6]);
#pragma unroll
    for (int off = 8; off > 0; off >>= 1) m = fmaxf(m, __shfl_xor(m, off));

    float e[7];
    float se = 0.f, py = 0.f;
#pragma unroll
    for (int i = 0; i < 7; ++i) {
      const bool valid = (i < 6) | v6;
      e[i] = valid ? __expf(v[i] - m) : 0.f;
      se += e[i];
      if (i * 16 + r == yr) py = v[i];
    }
#pragma unroll
    for (int off = 8; off > 0; off >>= 1) {
      se += __shfl_xor(se, off);
      py += __shfl_xor(py, off);
    }
    const float ce  = m + __logf(se) - py;
    const float inv = 1.f / se;

    const float* __restrict__ uty = Ut + yr * NC;
    float ap = 0.f;
    float s[7];
#pragma unroll
    for (int i = 0; i < 7; ++i) {
      const int col = i * 16 + r;
      s[i] = e[i] * inv - (col == yr ? 1.f : 0.f);
      const float u = ((i < 6) | v6) ? uty[col] : 0.f;
      ap = fmaf(s[i], u, ap);
    }
#pragma unroll
    for (int off = 8; off > 0; off >>= 1) ap += __shfl_xor(ap, off);

    if (r == 0) {
      rowce[row] = ce;   // plain stores, no global atomics
      rowap[row] = ap;
    }
#pragma unroll
    for (int i = 0; i < 7; ++i) atomicAdd(&sp[i * 16 + r], s[i]);
  }
  __syncthreads();
  if (t < NCP) S_part[(size_t)t * 512 + blockIdx.x] = sp[t];  // column-major
}

// ---- red: blocks 0..111 S columns; 112/113 ce/ap sums; 114..117 cls_ap -----
__global__ __launch_bounds__(256) void k_red(const int* __restrict__ Y,
                                             const float* __restrict__ S_part,
                                             const float* __restrict__ rowce,
                                             const float* __restrict__ rowap,
                                             float* __restrict__ stot,
                                             float* __restrict__ sums,
                                             float* __restrict__ cls_ap) {
  __shared__ float red[256];
  const int bid = blockIdx.x;
  const int t   = threadIdx.x;
  if (bid < NCP) {
    float s = S_part[(size_t)bid * 512 + t] + S_part[(size_t)bid * 512 + 256 + t];
    red[t] = s;
    __syncthreads();
    for (int off = 128; off > 0; off >>= 1) {
      if (t < off) red[t] += red[t + off];
      __syncthreads();
    }
    if (t == 0) stot[bid] = red[0];
  } else if (bid < 114) {
    const float* __restrict__ src = (bid == 112) ? rowce : rowap;
    float s = 0.f;
    for (int i = t; i < NB; i += 256) s += src[i];
    red[t] = s;
    __syncthreads();
    for (int off = 128; off > 0; off >>= 1) {
      if (t < off) red[t] += red[t + off];
      __syncthreads();
    }
    if (t == 0) sums[bid - 112] = red[0];
  } else {
    const int base = (bid - 114) * 2048;
#pragma unroll
    for (int q = 0; q < 8; ++q) {
      const int i = base + q * 256 + t;
      atomicAdd(&cls_ap[Y[i]], rowap[i]);
    }
  }
}

// ---- final: V[c] dot, loss -------------------------------------------------
__global__ __launch_bounds__(256) void k_final(const int* __restrict__ hist,
                                               const float* __restrict__ Ut,
                                               const float* __restrict__ stot,
                                               const float* __restrict__ sums,
                                               const float* __restrict__ cls_ap,
                                               float* __restrict__ out) {
  __shared__ float st[NC];
  __shared__ float red2[256];
  const int t = threadIdx.x;
  if (t < NC) st[t] = stot[t];
  __syncthreads();
  float part = 0.f;
  if (t < NC) {
    float dot = 0.f;
    for (int c = 0; c < NC; ++c) dot = fmaf(st[c], Ut[t * NC + c], dot);
    part = (float)hist[t] * (dot - cls_ap[t]);
  }
  red2[t] = part;
  __syncthreads();
  for (int off = 128; off > 0; off >>= 1) {
    if (t < off) red2[t] += red2[t + off];
    __syncthreads();
  }
  if (t == 0) {
    out[0] = (sums[0] + ALPHA_ * (red2[0] - sums[1] + (float)NB * MARGIN_)) /
             (float)NB;
  }
}

extern "C" void kernel_launch(void* const* d_in, const int* in_sizes, int n_in,
                              void* d_out, int out_size, void* d_ws,
                              size_t ws_size, hipStream_t stream) {
  const float* X = (const float*)d_in[0];
  const float* W = (const float*)d_in[1];
  const float* A = (const float*)d_in[2];
  const int*   Y = (const int*)d_in[3];
  float* out = (float*)d_out;
  char*  ws  = (char*)d_ws;

  float*          Gp     = (float*)(ws + 0);        // 8*100*112*4 = 358400 B
  float*          pap    = (float*)(ws + 358400);   // 358400 B
  float*          Ut     = (float*)(ws + 716800);   // 40000 B
  float*          cls_ap = (float*)(ws + 756800);   // zstrip part 1 (128 f)
  int*            hist   = (int*)(ws + 757312);     // zstrip part 2 (128 i)
  float*          sums   = (float*)(ws + 757824);   // zstrip part 3 (128 f)
  float*          stot   = (float*)(ws + 758336);   // 448 B (plain stores)
  unsigned short* Wtf    = (unsigned short*)(ws + 760832);  // 458752 B
  float*          S_part = (float*)(ws + 1219584);  // 112*512*4 = 229376 B
  float*          rowce  = (float*)(ws + 1448960);  // 32768 B
  float*          rowap  = (float*)(ws + 1481728);  // 32768 B

  k_prepA<<<913, 256, 0, stream>>>(W, A, Wtf, Gp, pap, cls_ap);
  k_prep2<<<NC, 128, 0, stream>>>(Gp, pap, Y, Ut, hist);
  k_main<<<NB / 16, 512, 0, stream>>>(X, Wtf, Y, Ut, S_part, rowce, rowap);
  k_red<<<118, 256, 0, stream>>>(Y, S_part, rowce, rowap, stot, sums, cls_ap);
  k_final<<<1, 256, 0, stream>>>(hist, Ut, stot, sums, cls_ap, out);
}

// Round 16
// 60.088 us; speedup vs baseline: 1.8759x; 1.8759x over previous
//
#include <hip/hip_runtime.h>
#include <math.h>

#define NB      8192
#define ND      2048
#define NC      100
#define NCP     112
#define ALPHA_  2.0f
#define MARGIN_ 0.05f

typedef short bf16x8 __attribute__((ext_vector_type(8)));
typedef float f32x4 __attribute__((ext_vector_type(4)));

static __device__ __forceinline__ unsigned short f2bf(float f) {
  unsigned u = __float_as_uint(f);
  u += 0x7FFFu + ((u >> 16) & 1u);
  return (unsigned short)(u >> 16);
}

// ---- prepW: Wtf fragment-major bf16; block 0 zeroes 384-float ACC strip ----
__global__ __launch_bounds__(256) void k_prepW(const float* __restrict__ W,
                                               unsigned short* __restrict__ Wtf,
                                               float* __restrict__ zstrip) {
  const int t = threadIdx.x;
  if (blockIdx.x == 0) {
    for (int i = t; i < 384; i += 256) zstrip[i] = 0.f;  // cls_ap, hist, sums
  }
  const int f   = blockIdx.x * 256 + t;  // 0..28671
  const int ws  = f / 448;
  const int rem = f - ws * 448;
  const int i   = rem >> 6;
  const int l   = rem & 63;
  const int col = i * 16 + (l & 15);
  const int k0  = ws * 32 + (l >> 4) * 8;
  bf16x8 v;
#pragma unroll
  for (int j = 0; j < 8; ++j)
    v[j] = (short)((col < NC) ? f2bf(W[(size_t)(k0 + j) * NC + col]) : 0);
  *(bf16x8*)(Wtf + (size_t)f * 8) = v;
}

// ---- prepG: G2 = W^T W, pa2 = A @ W (112x112 tiles via MFMA) ---------------
__global__ __launch_bounds__(512) void k_prepG(const unsigned short* __restrict__ Wtf,
                                               const float* __restrict__ A,
                                               float* __restrict__ G2,
                                               float* __restrict__ pa2) {
  __shared__ float red[8][8][64];
  const int t    = threadIdx.x;
  const int w    = t >> 6;
  const int lane = t & 63;
  const int ti   = blockIdx.x / 7;
  const int tj   = blockIdx.x % 7;
  const int arow = ti * 16 + (lane & 15);

  f32x4 accG = {0.f, 0.f, 0.f, 0.f};
  f32x4 accP = {0.f, 0.f, 0.f, 0.f};
#pragma unroll
  for (int s = 0; s < 8; ++s) {
    const int ws = w * 8 + s;
    const bf16x8 afr = *(const bf16x8*)(Wtf + (size_t)(ws * 7 + ti) * 512 + lane * 8);
    const bf16x8 bfr = *(const bf16x8*)(Wtf + (size_t)(ws * 7 + tj) * 512 + lane * 8);
    accG = __builtin_amdgcn_mfma_f32_16x16x32_bf16(afr, bfr, accG, 0, 0, 0);
    bf16x8 aa;
    if (arow < NC) {
      const float* __restrict__ ar =
          A + (size_t)arow * ND + ws * 32 + (lane >> 4) * 8;
      const float4 v0 = *(const float4*)(ar);
      const float4 v1 = *(const float4*)(ar + 4);
      aa[0] = (short)f2bf(v0.x); aa[1] = (short)f2bf(v0.y);
      aa[2] = (short)f2bf(v0.z); aa[3] = (short)f2bf(v0.w);
      aa[4] = (short)f2bf(v1.x); aa[5] = (short)f2bf(v1.y);
      aa[6] = (short)f2bf(v1.z); aa[7] = (short)f2bf(v1.w);
    } else {
#pragma unroll
      for (int q = 0; q < 8; ++q) aa[q] = 0;
    }
    accP = __builtin_amdgcn_mfma_f32_16x16x32_bf16(aa, bfr, accP, 0, 0, 0);
  }
#pragma unroll
  for (int rg = 0; rg < 4; ++rg) {
    red[w][rg][lane]     = accG[rg];
    red[w][4 + rg][lane] = accP[rg];
  }
  __syncthreads();
  if (w < 2) {
    const int vb = w * 4;
    float* __restrict__ dst = (w == 0) ? G2 : pa2;
#pragma unroll
    for (int rg = 0; rg < 4; ++rg) {
      float s = 0.f;
#pragma unroll
      for (int w2 = 0; w2 < 8; ++w2) s += red[w2][vb + rg][lane];
      const int row = ti * 16 + (lane >> 4) * 4 + rg;
      dst[row * NCP + tj * 16 + (lane & 15)] = s;
    }
  }
}

// ---- prep2: hist slice + T=softmax(pa)-I ; Ut[cp][r] = (G T^T)[r][cp] ------
__global__ __launch_bounds__(128) void k_prep2(const float* __restrict__ G2,
                                               const float* __restrict__ pa2,
                                               const int* __restrict__ Y,
                                               float* __restrict__ Ut,
                                               int* __restrict__ hist) {
  __shared__ float vals[128];
  __shared__ float tl[128];
  const int cp = blockIdx.x;
  const int t  = threadIdx.x;
  {
    const int i = cp * 82 + t;
    if (t < 82 && i < NB) atomicAdd(&hist[Y[i]], 1);
  }
  const float v = (t < NC) ? pa2[cp * NCP + t] : -INFINITY;
  vals[t] = v;
  __syncthreads();
  float m = -INFINITY;
  for (int c = 0; c < NC; ++c) m = fmaxf(m, vals[c]);
  float se = 0.f;
  for (int c = 0; c < NC; ++c) se += __expf(vals[c] - m);
  tl[t] = (t < NC) ? (__expf(v - m) / se - (t == cp ? 1.f : 0.f)) : 0.f;
  __syncthreads();
  if (t < NC) {
    float u = 0.f;
    for (int c = 0; c < NC; ++c) u = fmaf(G2[c * NCP + t], tl[c], u);
    Ut[cp * NC + t] = u;
  }
}

// ---- main: r10 verbatim — 8 waves x 256-K, B dbuf, atomic-free store tail --
__global__ __launch_bounds__(512, 4) void k_main(const float* __restrict__ X,
                                                 const unsigned short* __restrict__ Wtf,
                                                 const int* __restrict__ Y,
                                                 const float* __restrict__ Ut,
                                                 float* __restrict__ S_part,
                                                 float* __restrict__ rowce,
                                                 float* __restrict__ rowap) {
  __shared__ __align__(16) char smem[65536];  // 8 x 8KB wave slabs; reused
  const int t    = threadIdx.x;
  const int w    = t >> 6;     // wave 0..7 = K-slice (256 K each)
  const int lane = t & 63;
  const int row0 = blockIdx.x * 16;
  char* __restrict__ wbase = smem + w * 8192;

  // issue first B-fragment batch BEFORE the X stage (independent of LDS)
  const unsigned short* __restrict__ bp0 =
      Wtf + (size_t)(w * 8 * 7) * 512 + lane * 8;
  bf16x8 cur[7], nxt[7];
#pragma unroll
  for (int i = 0; i < 7; ++i) cur[i] = *(const bf16x8*)(bp0 + i * 512);

  // ---- per-wave stage: 16 rows x 256 K, f32 -> bf16, XOR-swizzled [row][k] --
  {
    const int srow = lane >> 2;
    const int sc   = lane & 3;
    const float* __restrict__ xr =
        X + (size_t)(row0 + srow) * ND + w * 256 + sc * 8;
    const int wsz = (srow & 7) << 4;
#pragma unroll
    for (int j = 0; j < 8; ++j) {
      const float4 v0 = *(const float4*)(xr + j * 32);
      const float4 v1 = *(const float4*)(xr + j * 32 + 4);
      bf16x8 p;
      p[0] = (short)f2bf(v0.x); p[1] = (short)f2bf(v0.y);
      p[2] = (short)f2bf(v0.z); p[3] = (short)f2bf(v0.w);
      p[4] = (short)f2bf(v1.x); p[5] = (short)f2bf(v1.y);
      p[6] = (short)f2bf(v1.z); p[7] = (short)f2bf(v1.w);
      *(bf16x8*)(wbase + srow * 512 + ((sc * 16 + j * 64) ^ wsz)) = p;
    }
  }
  // no barrier: slab is wave-private (ds_write->ds_read ordered in-wave)

  const int r = lane & 15;
  const int g = lane >> 4;

  f32x4 acc[7];
  const f32x4 z = {0.f, 0.f, 0.f, 0.f};
#pragma unroll
  for (int i = 0; i < 7; ++i) acc[i] = z;

  const char* __restrict__ abase = wbase + r * 512;
  const int asz = (r & 7) << 4;
#pragma unroll
  for (int s = 0; s < 8; ++s) {
    const bf16x8 xf = *(const bf16x8*)(abase + ((s * 64 + g * 16) ^ asz));
    if (s < 7) {
      const unsigned short* __restrict__ bpn = bp0 + (size_t)(s + 1) * 7 * 512;
#pragma unroll
      for (int i = 0; i < 7; ++i) nxt[i] = *(const bf16x8*)(bpn + i * 512);
    }
#pragma unroll
    for (int i = 0; i < 7; ++i)
      acc[i] = __builtin_amdgcn_mfma_f32_16x16x32_bf16(xf, cur[i], acc[i], 0, 0, 0);
#pragma unroll
    for (int i = 0; i < 7; ++i) cur[i] = nxt[i];
  }
  __syncthreads();  // all waves done with slabs -> reuse for reduction

  float* __restrict__ redp = (float*)smem;            // [8][7][4][64] = 57344 B
  float* __restrict__ sp   = (float*)(smem + 57344);  // [112] column partials
#pragma unroll
  for (int i = 0; i < 7; ++i)
#pragma unroll
    for (int j = 0; j < 4; ++j)
      redp[(w * 7 + i) * 256 + j * 64 + lane] = acc[i][j];
  if (t < NCP) sp[t] = 0.f;
  __syncthreads();

  // epilogue: waves 0..3 each own j = w (rows g*4 + j)
  if (w < 4) {
    const int j = w;
    float v[7];
#pragma unroll
    for (int i = 0; i < 7; ++i) {
      float s = 0.f;
#pragma unroll
      for (int w2 = 0; w2 < 8; ++w2)
        s += redp[(w2 * 7 + i) * 256 + j * 64 + lane];
      v[i] = s;
    }
    const bool v6  = (96 + r) < NC;
    const int  row = row0 + g * 4 + j;
    const int  yr  = Y[row];

    float m = -INFINITY;
#pragma unroll
    for (int i = 0; i < 6; ++i) m = fmaxf(m, v[i]);
    if (v6) m = fmaxf(m, v[6]);
#pragma unroll
    for (int off = 8; off > 0; off >>= 1) m = fmaxf(m, __shfl_xor(m, off));

    float e[7];
    float se = 0.f, py = 0.f;
#pragma unroll
    for (int i = 0; i < 7; ++i) {
      const bool valid = (i < 6) | v6;
      e[i] = valid ? __expf(v[i] - m) : 0.f;
      se += e[i];
      if (i * 16 + r == yr) py = v[i];
    }
#pragma unroll
    for (int off = 8; off > 0; off >>= 1) {
      se += __shfl_xor(se, off);
      py += __shfl_xor(py, off);
    }
    const float ce  = m + __logf(se) - py;
    const float inv = 1.f / se;

    const float* __restrict__ uty = Ut + yr * NC;
    float ap = 0.f;
    float s[7];
#pragma unroll
    for (int i = 0; i < 7; ++i) {
      const int col = i * 16 + r;
      s[i] = e[i] * inv - (col == yr ? 1.f : 0.f);
      const float u = ((i < 6) | v6) ? uty[col] : 0.f;
      ap = fmaf(s[i], u, ap);
    }
#pragma unroll
    for (int off = 8; off > 0; off >>= 1) ap += __shfl_xor(ap, off);

    if (r == 0) {
      rowce[row] = ce;   // plain stores, no global atomics
      rowap[row] = ap;
    }
#pragma unroll
    for (int i = 0; i < 7; ++i) atomicAdd(&sp[i * 16 + r], s[i]);
  }
  __syncthreads();
  if (t < NCP) S_part[(size_t)t * 512 + blockIdx.x] = sp[t];  // column-major
}

// ---- red: 0..111 S columns | 112..127 per-block cls_ap/ce/ap (LDS-agg) -----
__global__ __launch_bounds__(256) void k_red(const int* __restrict__ Y,
                                             const float* __restrict__ S_part,
                                             const float* __restrict__ rowce,
                                             const float* __restrict__ rowap,
                                             float* __restrict__ stot,
                                             float* __restrict__ sums,
                                             float* __restrict__ cls_ap) {
  __shared__ float red[256];
  __shared__ float clsap[128];
  const int bid = blockIdx.x;
  const int t   = threadIdx.x;
  if (bid < NCP) {
    red[t] = S_part[(size_t)bid * 512 + t] + S_part[(size_t)bid * 512 + 256 + t];
    __syncthreads();
    for (int off = 128; off > 0; off >>= 1) {
      if (t < off) red[t] += red[t + off];
      __syncthreads();
    }
    if (t == 0) stot[bid] = red[0];
  } else {
    // 16 blocks x 512 rows: LDS-aggregate cls_ap, ce, ap
    const int base = (bid - NCP) * 512;
    if (t < 128) clsap[t] = 0.f;
    __syncthreads();
    float ces = 0.f, aps = 0.f;
#pragma unroll
    for (int q = 0; q < 2; ++q) {
      const int i = base + q * 256 + t;
      const float a = rowap[i];
      ces += rowce[i];
      aps += a;
      atomicAdd(&clsap[Y[i]], a);
    }
    red[t] = ces;
    __syncthreads();
    for (int off = 128; off > 0; off >>= 1) {
      if (t < off) red[t] += red[t + off];
      __syncthreads();
    }
    if (t == 0) atomicAdd(&sums[0], red[0]);
    __syncthreads();
    red[t] = aps;
    __syncthreads();
    for (int off = 128; off > 0; off >>= 1) {
      if (t < off) red[t] += red[t + off];
      __syncthreads();
    }
    if (t == 0) atomicAdd(&sums[1], red[0]);
    if (t < NC) atomicAdd(&cls_ap[t], clsap[t]);
  }
}

// ---- final: tiny — V[c] dot + loss -----------------------------------------
__global__ __launch_bounds__(256) void k_final(const int* __restrict__ hist,
                                               const float* __restrict__ Ut,
                                               const float* __restrict__ stot,
                                               const float* __restrict__ sums,
                                               const float* __restrict__ cls_ap,
                                               float* __restrict__ out) {
  __shared__ float st[NC];
  __shared__ float red2[256];
  const int t = threadIdx.x;
  if (t < NC) st[t] = stot[t];
  __syncthreads();
  float part = 0.f;
  if (t < NC) {
    float dot = 0.f;
    for (int c = 0; c < NC; ++c) dot = fmaf(st[c], Ut[t * NC + c], dot);
    part = (float)hist[t] * (dot - cls_ap[t]);
  }
  red2[t] = part;
  __syncthreads();
  for (int off = 128; off > 0; off >>= 1) {
    if (t < off) red2[t] += red2[t + off];
    __syncthreads();
  }
  if (t == 0) {
    out[0] = (sums[0] + ALPHA_ * (red2[0] - sums[1] + (float)NB * MARGIN_)) /
             (float)NB;
  }
}

extern "C" void kernel_launch(void* const* d_in, const int* in_sizes, int n_in,
                              void* d_out, int out_size, void* d_ws,
                              size_t ws_size, hipStream_t stream) {
  const float* X = (const float*)d_in[0];
  const float* W = (const float*)d_in[1];
  const float* A = (const float*)d_in[2];
  const int*   Y = (const int*)d_in[3];
  float* out = (float*)d_out;
  char*  ws  = (char*)d_ws;

  float*          G2     = (float*)(ws + 0);       // 50176 B
  float*          pa2    = (float*)(ws + 50176);   // 50176 B
  float*          Ut     = (float*)(ws + 100352);  // 40000 B
  float*          cls_ap = (float*)(ws + 140800);  // 512 B -- zstrip[0:128]
  int*            hist   = (int*)(ws + 141312);    // 512 B -- zstrip[128:256]
  float*          sums   = (float*)(ws + 141824);  // 512 B -- zstrip[256:384]
  float*          stot   = (float*)(ws + 142336);  // 448 B (plain stores)
  unsigned short* Wtf    = (unsigned short*)(ws + 147456);  // 458752 B
  float*          S_part = (float*)(ws + 606208);  // 112*512*4 = 229376 B
  float*          rowce  = (float*)(ws + 835584);  // 32768 B
  float*          rowap  = (float*)(ws + 868352);  // 32768 B

  k_prepW<<<112, 256, 0, stream>>>(W, Wtf, cls_ap);
  k_prepG<<<49, 512, 0, stream>>>(Wtf, A, G2, pa2);
  k_prep2<<<NC, 128, 0, stream>>>(G2, pa2, Y, Ut, hist);
  k_main<<<NB / 16, 512, 0, stream>>>(X, Wtf, Y, Ut, S_part, rowce, rowap);
  k_red<<<128, 256, 0, stream>>>(Y, S_part, rowce, rowap, stot, sums, cls_ap);
  k_final<<<1, 256, 0, stream>>>(hist, Ut, stot, sums, cls_ap, out);
}